// Round 6
// baseline (192.329 us; speedup 1.0000x reference)
//
#include <hip/hip_runtime.h>
#include <stdint.h>

// ---------- types ----------
typedef __bf16 bf16x8 __attribute__((ext_vector_type(8)));
typedef float  f32x4  __attribute__((ext_vector_type(4)));
typedef unsigned short u16x4 __attribute__((ext_vector_type(4)));

#define MFMA16(a,b,c) __builtin_amdgcn_mfma_f32_16x16x32_bf16((a),(b),(c),0,0,0)

constexpr int Bc  = 4;
constexpr int Tc  = 2048;
constexpr int Dc  = 768;
constexpr int Hc  = 12;
constexpr int NTOK = Bc * Tc;        // 8192
constexpr int QKV_LD = 3 * Dc;       // 2304

static __device__ __forceinline__ unsigned short f2bf(float f){
  unsigned u = __float_as_uint(f);
  u += 0x7fffu + ((u >> 16) & 1u);   // RNE
  return (unsigned short)(u >> 16);
}

static __device__ __forceinline__ float exp2a(float x){
  float r; asm("v_exp_f32 %0, %1" : "=v"(r) : "v"(x)); return r;
}

static __device__ __forceinline__ unsigned cvtpk_bf16(float lo, float hi){
  unsigned r; asm("v_cvt_pk_bf16_f32 %0, %1, %2" : "=v"(r) : "v"(lo), "v"(hi)); return r;
}

static __device__ __forceinline__ void gload_lds16(const void* g, void* l){
  __builtin_amdgcn_global_load_lds((__attribute__((address_space(1))) void*)g,
                                   (__attribute__((address_space(3))) void*)l,
                                   16, 0, 0);
}

// ---------- f32 -> bf16 conversion ----------
__global__ void cvt_bf16(const float* __restrict__ src, unsigned short* __restrict__ dst,
                         int n4, float scale){
  int i = blockIdx.x * blockDim.x + threadIdx.x;
  if (i >= n4) return;
  float4 v = reinterpret_cast<const float4*>(src)[i];
  ushort4 o;
  o.x = f2bf(v.x * scale); o.y = f2bf(v.y * scale);
  o.z = f2bf(v.z * scale); o.w = f2bf(v.w * scale);
  reinterpret_cast<ushort4*>(dst)[i] = o;
}

// ---------- mask expansion with layout auto-detection ----------
__global__ void expand_mask(const unsigned* __restrict__ raw, int* __restrict__ out, int n){
  __shared__ int sInt, sFlt;
  int t = threadIdx.x;
  if (t == 0){ sInt = 1; sFlt = 1; }
  __syncthreads();
  int okI = 1, okF = 1;
  for (int i = t; i < n/4; i += blockDim.x){
    unsigned u = raw[i];
    okI &= (u <= 1u);
    okF &= (u == 0u || u == 0x3f800000u);
  }
  if (!okI) atomicAnd(&sInt, 0);
  if (!okF) atomicAnd(&sFlt, 0);
  __syncthreads();
  if (sInt || sFlt){
    for (int i = t; i < n; i += blockDim.x) out[i] = (raw[i] != 0u);
  } else {
    const unsigned char* rb = (const unsigned char*)raw;
    for (int i = t; i < n; i += blockDim.x) out[i] = (rb[i] != 0);
  }
}

// ---------- bf16 NT GEMM (verified round 0) ----------
template<typename CT>
__global__ __launch_bounds__(256) void gemm_bt(const unsigned short* __restrict__ A,
                                               const unsigned short* __restrict__ Bm,
                                               CT* __restrict__ C,
                                               int M, int N, int K){
  __shared__ unsigned short As[128*32];
  __shared__ unsigned short Bs[128*32];
  const int t = threadIdx.x;
  const int w = t >> 6, l = t & 63;
  const int wr = w >> 1, wc = w & 1;
  const int br = blockIdx.y * 128, bc = blockIdx.x * 128;

  f32x4 acc[4][4];
  const f32x4 fz = {0.f,0.f,0.f,0.f};
  #pragma unroll
  for (int m=0;m<4;m++)
    #pragma unroll
    for (int n=0;n<4;n++) acc[m][n] = fz;

  const int lrow = l >> 2;
  const int lk   = (l & 3) * 8;
  const int fr   = l & 15;
  const int fk   = (l >> 4) * 8;

  for (int k0 = 0; k0 < K; k0 += 32){
    #pragma unroll
    for (int it = 0; it < 2; ++it){
      const int rb = it*64 + w*16;
      gload_lds16(A  + (size_t)(br + rb + lrow)*K + k0 + lk, &As[rb*32]);
      gload_lds16(Bm + (size_t)(bc + rb + lrow)*K + k0 + lk, &Bs[rb*32]);
    }
    __syncthreads();
    bf16x8 a[4], b[4];
    #pragma unroll
    for (int m=0;m<4;m++)
      a[m] = *reinterpret_cast<const bf16x8*>(&As[(wr*64 + m*16 + fr)*32 + fk]);
    #pragma unroll
    for (int n=0;n<4;n++)
      b[n] = *reinterpret_cast<const bf16x8*>(&Bs[(wc*64 + n*16 + fr)*32 + fk]);
    #pragma unroll
    for (int m=0;m<4;m++)
      #pragma unroll
      for (int n=0;n<4;n++)
        acc[m][n] = MFMA16(a[m], b[n], acc[m][n]);
    __syncthreads();
  }

  const int orow0 = br + wr*64 + (l >> 4)*4;
  const int ocol0 = bc + wc*64 + (l & 15);
  #pragma unroll
  for (int m=0;m<4;m++)
    #pragma unroll
    for (int n=0;n<4;n++)
      #pragma unroll
      for (int r=0;r<4;r++){
        const size_t idx = (size_t)(orow0 + m*16 + r) * N + (ocol0 + n*16);
        float v = acc[m][n][r];
        if constexpr (sizeof(CT) == 2) C[idx] = (CT)f2bf(v);
        else                           C[idx] = v;
      }
}

// ---------- V transpose: QKV V-region -> VtG[(b*H+h)*64 + d][T] ----------
// FIX (round 4 bug): store phase now covers BOTH 32-token halves of the chunk.
__global__ __launch_bounds__(256) void vtrans(const unsigned short* __restrict__ QKV,
                                              unsigned short* __restrict__ VtG){
  __shared__ unsigned short st[64][72];   // padded rows
  const int t = threadIdx.x;
  const int token0 = blockIdx.x * 64;
  const int bh = blockIdx.y;
  const int b = bh / Hc, h = bh - b * Hc;
  const size_t tokbase = (size_t)b * Tc;

  const int tok = t >> 2;
  const unsigned short* src = QKV + (tokbase + token0 + tok) * (size_t)QKV_LD + 1536 + h*64;
  #pragma unroll
  for (int i = 0; i < 2; ++i){
    const int ul = (t & 3)*2 + i;
    *reinterpret_cast<uint4*>(&st[tok][ul*8]) =
        *reinterpret_cast<const uint4*>(src + ul*8);
  }
  __syncthreads();
  const int d = t >> 2;
  #pragma unroll
  for (int half = 0; half < 2; ++half){
    union { unsigned short s[8]; uint4 q; } tmp;
    const int tk0 = (t & 3)*8 + half*32;
    #pragma unroll
    for (int j = 0; j < 8; ++j)
      tmp.s[j] = st[tk0 + j][d];
    *reinterpret_cast<uint4*>(VtG + ((size_t)(bh*64 + d))*Tc + token0 + tk0) = tmp.q;
  }
}

// ---------- flash attention: 3-buffer, counted-vmcnt raw barriers ----------
// grid (T/128, B*H); 4 waves x 32 q-rows; KV chunk = 64.
// Per iter c: QK(c) -> issue stage(c+2) -> softmax(c) -> PV(c) -> Ms(c+2)
//             -> s_waitcnt vmcnt(4) + raw s_barrier  (stage(c+1) ready, c+2 in flight)
__global__ __launch_bounds__(256, 3) void attn(const unsigned short* __restrict__ QKV,
                                               const unsigned short* __restrict__ VtG,
                                               const int* __restrict__ mask,
                                               unsigned short* __restrict__ AO){
  __shared__ unsigned short Ks[3][64*64];  // K chunk, source-swizzled (16B units: c ^= row&7)
  __shared__ unsigned short Vs[3][64*64];  // V^T chunk [d][key], same source swizzle
  __shared__ float Ms[3][64];              // additive key-mask bias

  const int t = threadIdx.x, w = t >> 6, l = t & 63;
  const int bh = blockIdx.y;
  const int b  = bh / Hc, h = bh - b * Hc;
  const int q0 = blockIdx.x * 128 + w * 32;
  const int fr = l & 15, fg = l >> 4;

  const size_t tokbase = (size_t)b * Tc;
  const unsigned short* Qp = QKV + (tokbase + q0) * (size_t)QKV_LD + h*64;
  const unsigned short* Kbase = QKV + tokbase * (size_t)QKV_LD + h*64 + 768;
  const unsigned short* VtB = VtG + (size_t)(bh*64) * Tc;
  const int* bm = mask + b * Tc;

  // Q fragments: Q[q=mc*16+fr][k=ks*32+fg*8+j]
  bf16x8 qa[2][2];
  #pragma unroll
  for (int mc=0; mc<2; mc++)
    #pragma unroll
    for (int ks=0; ks<2; ks++)
      qa[mc][ks] = *reinterpret_cast<const bf16x8*>(
          Qp + (size_t)(mc*16+fr)*QKV_LD + ks*32 + fg*8);

  // wave 0: preload all 32 chunk-mask bits for its lane's key slot
  unsigned bits = 0;
  if (w == 0){
    #pragma unroll
    for (int cc = 0; cc < 32; ++cc)
      bits |= (unsigned)(bm[cc*64 + l] != 0) << cc;
  }

  const f32x4 fz = {0.f,0.f,0.f,0.f};
  f32x4 accT[2][4];
  #pragma unroll
  for (int mc=0; mc<2; mc++)
    #pragma unroll
    for (int n=0; n<4; n++) accT[mc][n] = fz;
  float mrow[2] = {-1e30f, -1e30f};
  float lsum[2] = {0.f, 0.f};

  // ---- staging helpers (4 gload_lds16 per thread per chunk, all waves) ----
  const int srow = l >> 3, scol = (l & 7) ^ (l >> 3);   // source swizzle
  auto stage = [&](int c){
    const int key0 = c * 64, buf = c % 3;
    #pragma unroll
    for (int i=0; i<2; i++){
      const int rb = w*16 + i*8;      // K rows
      gload_lds16(Kbase + (size_t)(key0 + rb + srow)*QKV_LD + scol*8,
                  &Ks[buf][rb*64]);
    }
    #pragma unroll
    for (int i=0; i<2; i++){
      const int rb = (w*2 + i)*8;     // V^T rows (d)
      gload_lds16(VtB + (size_t)(rb + srow)*Tc + key0 + scol*8,
                  &Vs[buf][rb*64]);
    }
  };

  // ---- prologue: stage chunks 0,1; Ms[0],Ms[1]
  stage(0); stage(1);
  if (w == 0){
    Ms[0][l] = (bits & 1u) ? -1e9f : 0.f;
    Ms[1][l] = (bits & 2u) ? -1e9f : 0.f;
  }
  asm volatile("s_waitcnt vmcnt(4) lgkmcnt(0)" ::: "memory");
  __builtin_amdgcn_s_barrier();
  asm volatile("" ::: "memory");

  for (int c = 0; c < 32; ++c){
    const int cb = c % 3;

    // ---- QK^T swapped: S^T[key][q], mask bias as C-init
    f32x4 S[2][4];
    __builtin_amdgcn_s_setprio(1);
    #pragma unroll
    for (int g=0; g<4; g++){
      f32x4 mb = *reinterpret_cast<const f32x4*>(&Ms[cb][g*16 + fg*4]);
      S[0][g] = mb; S[1][g] = mb;
      #pragma unroll
      for (int ks=0; ks<2; ks++){
        const int row = g*16 + fr;
        bf16x8 kf = *reinterpret_cast<const bf16x8*>(
            &Ks[cb][row*64 + (((ks*4+fg) ^ (row&7))*8)]);
        S[0][g] = MFMA16(kf, qa[0][ks], S[0][g]);
        S[1][g] = MFMA16(kf, qa[1][ks], S[1][g]);
      }
    }
    __builtin_amdgcn_s_setprio(0);

    // ---- issue stage(c+2): in flight across ~1.5 iterations
    if (c + 2 < 32) stage(c + 2);

    // ---- softmax(c): in-lane 16 keys + 2 shfls; P packed in regs
    unsigned pkAll[2][4][2];
    #pragma unroll
    for (int mc=0; mc<2; mc++){
      float cm = -3e38f;
      #pragma unroll
      for (int g=0; g<4; g++)
        cm = fmaxf(cm, fmaxf(fmaxf(S[mc][g][0], S[mc][g][1]),
                             fmaxf(S[mc][g][2], S[mc][g][3])));
      cm = fmaxf(cm, __shfl_xor(cm, 16));
      cm = fmaxf(cm, __shfl_xor(cm, 32));
      if (!__all(cm <= mrow[mc] + 8.0f)){     // defer-max (T13)
        const float nm = fmaxf(mrow[mc], cm);
        const float sc = exp2a(mrow[mc] - nm);
        lsum[mc] *= sc;
        #pragma unroll
        for (int n=0; n<4; n++) accT[mc][n] = accT[mc][n] * sc;
        mrow[mc] = nm;
      }
      float ps = 0.f;
      #pragma unroll
      for (int g=0; g<4; g++){
        const float p0 = exp2a(S[mc][g][0] - mrow[mc]);
        const float p1 = exp2a(S[mc][g][1] - mrow[mc]);
        const float p2 = exp2a(S[mc][g][2] - mrow[mc]);
        const float p3 = exp2a(S[mc][g][3] - mrow[mc]);
        ps += (p0 + p1) + (p2 + p3);
        pkAll[mc][g][0] = cvtpk_bf16(p0, p1);
        pkAll[mc][g][1] = cvtpk_bf16(p2, p3);
      }
      ps += __shfl_xor(ps, 16);
      ps += __shfl_xor(ps, 32);
      lsum[mc] += ps;
    }

    // ---- PV swapped: O^T += V^T * P^T (permuted k-order, lane-local P)
    __builtin_amdgcn_s_setprio(1);
    #pragma unroll
    for (int ks2=0; ks2<2; ks2++){
      union PBu { unsigned u[4]; bf16x8 v; } pb0, pb1;
      pb0.u[0] = pkAll[0][ks2*2][0];   pb0.u[1] = pkAll[0][ks2*2][1];
      pb0.u[2] = pkAll[0][ks2*2+1][0]; pb0.u[3] = pkAll[0][ks2*2+1][1];
      pb1.u[0] = pkAll[1][ks2*2][0];   pb1.u[1] = pkAll[1][ks2*2][1];
      pb1.u[2] = pkAll[1][ks2*2+1][0]; pb1.u[3] = pkAll[1][ks2*2+1][1];
      #pragma unroll
      for (int n=0; n<4; n++){
        const int row = n*16 + fr;
        union VA { u16x4 h[2]; bf16x8 v; } va;
        va.h[0] = *reinterpret_cast<const u16x4*>(
            &Vs[cb][row*64 + (((ks2*4     + (fg>>1)) ^ (row&7))*8) + (fg&1)*4]);
        va.h[1] = *reinterpret_cast<const u16x4*>(
            &Vs[cb][row*64 + (((ks2*4 + 2 + (fg>>1)) ^ (row&7))*8) + (fg&1)*4]);
        accT[0][n] = MFMA16(va.v, pb0.v, accT[0][n]);
        accT[1][n] = MFMA16(va.v, pb1.v, accT[1][n]);
      }
    }
    __builtin_amdgcn_s_setprio(0);

    // ---- Ms(c+2) from register bits (no VMEM)
    if (w == 0 && c + 2 < 32)
      Ms[(c+2)%3][l] = ((bits >> (c+2)) & 1u) ? -1e9f : 0.f;

    // ---- counted-vmcnt barrier: wait stage(c+1) only; stage(c+2) stays in flight
    if (c < 31){
      if (c < 30) asm volatile("s_waitcnt vmcnt(4) lgkmcnt(0)" ::: "memory");
      else        asm volatile("s_waitcnt vmcnt(0) lgkmcnt(0)" ::: "memory");
      __builtin_amdgcn_s_barrier();
      asm volatile("" ::: "memory");
    }
  }

  // ---- epilogue: normalize, zero q-padded rows, packed 8B stores
  #pragma unroll
  for (int mc=0; mc<2; mc++){
    const int qrow = q0 + mc*16 + fr;
    const int qm = bm[qrow];
    const float inv = (qm || lsum[mc] <= 0.f) ? 0.f : 1.f / lsum[mc];
    #pragma unroll
    for (int n=0; n<4; n++){
      ushort4 o;
      o.x = f2bf(accT[mc][n][0] * inv);
      o.y = f2bf(accT[mc][n][1] * inv);
      o.z = f2bf(accT[mc][n][2] * inv);
      o.w = f2bf(accT[mc][n][3] * inv);
      *reinterpret_cast<ushort4*>(
          &AO[(tokbase + qrow) * (size_t)Dc + h*64 + n*16 + fg*4]) = o;
    }
  }
}

// ---------- launch ----------
extern "C" void kernel_launch(void* const* d_in, const int* in_sizes, int n_in,
                              void* d_out, int out_size, void* d_ws, size_t ws_size,
                              hipStream_t stream){
  const float* h    = (const float*)d_in[0];
  const unsigned* m = (const unsigned*)d_in[1];
  const float* Wq   = (const float*)d_in[2];
  const float* Wk   = (const float*)d_in[3];
  const float* Wv   = (const float*)d_in[4];
  const float* Wo   = (const float*)d_in[5];
  float* out        = (float*)d_out;

  unsigned short* hb   = (unsigned short*)d_ws;       // 8192*768 (reused as VtG after gemm1)
  unsigned short* Wqkv = hb   + (size_t)NTOK * Dc;    // 2304*768
  unsigned short* Wob  = Wqkv + (size_t)QKV_LD * Dc;  // 768*768
  unsigned short* QKV  = Wob  + (size_t)Dc * Dc;      // 8192*2304
  unsigned short* AO   = QKV  + (size_t)NTOK * QKV_LD;// 8192*768
  int* mexp            = (int*)(AO + (size_t)NTOK * Dc);

  const size_t need = ((size_t)NTOK*Dc + (size_t)QKV_LD*Dc + (size_t)Dc*Dc +
                       (size_t)NTOK*QKV_LD + (size_t)NTOK*Dc) * 2 + (size_t)NTOK*4;
  if (ws_size < need) return;

  const int W2 = Dc * Dc;
  // Wq folded with (1/8)*log2e -> scores in log2 domain for exp2 softmax
  cvt_bf16<<<(NTOK*Dc/4 + 255)/256, 256, 0, stream>>>(h,  hb,          NTOK*Dc/4, 1.0f);
  cvt_bf16<<<(W2/4 + 255)/256,      256, 0, stream>>>(Wq, Wqkv,        W2/4, 0.125f*1.44269504f);
  cvt_bf16<<<(W2/4 + 255)/256,      256, 0, stream>>>(Wk, Wqkv + W2,   W2/4, 1.0f);
  cvt_bf16<<<(W2/4 + 255)/256,      256, 0, stream>>>(Wv, Wqkv + 2*W2, W2/4, 1.0f);
  cvt_bf16<<<(W2/4 + 255)/256,      256, 0, stream>>>(Wo, Wob,         W2/4, 1.0f);
  expand_mask<<<1, 256, 0, stream>>>(m, mexp, NTOK);

  gemm_bt<unsigned short><<<dim3(QKV_LD/128, NTOK/128), 256, 0, stream>>>(
      hb, Wqkv, QKV, NTOK, QKV_LD, Dc);

  // V^T into the now-dead hb buffer
  unsigned short* VtG = hb;
  vtrans<<<dim3(Tc/64, Bc*Hc), 256, 0, stream>>>(QKV, VtG);

  attn<<<dim3(Tc/128, Bc*Hc), 256, 0, stream>>>(QKV, VtG, mexp, AO);

  gemm_bt<float><<<dim3(Dc/128, NTOK/128), 256, 0, stream>>>(
      AO, Wob, out, NTOK, Dc, Dc);
}

// Round 7
// 192.151 us; speedup vs baseline: 1.0009x; 1.0009x over previous
//
#include <hip/hip_runtime.h>
#include <stdint.h>

// ---------- types ----------
typedef __bf16 bf16x8 __attribute__((ext_vector_type(8)));
typedef float  f32x4  __attribute__((ext_vector_type(4)));
typedef unsigned short u16x4 __attribute__((ext_vector_type(4)));

#define MFMA16(a,b,c) __builtin_amdgcn_mfma_f32_16x16x32_bf16((a),(b),(c),0,0,0)

constexpr int Bc  = 4;
constexpr int Tc  = 2048;
constexpr int Dc  = 768;
constexpr int Hc  = 12;
constexpr int NTOK = Bc * Tc;        // 8192
constexpr int QKV_LD = 3 * Dc;       // 2304

static __device__ __forceinline__ unsigned short f2bf(float f){
  unsigned u = __float_as_uint(f);
  u += 0x7fffu + ((u >> 16) & 1u);   // RNE
  return (unsigned short)(u >> 16);
}

static __device__ __forceinline__ float exp2a(float x){
  float r; asm("v_exp_f32 %0, %1" : "=v"(r) : "v"(x)); return r;
}

static __device__ __forceinline__ float max3f(float a, float b, float c){
  float r; asm("v_max3_f32 %0, %1, %2, %3" : "=v"(r) : "v"(a), "v"(b), "v"(c)); return r;
}

static __device__ __forceinline__ unsigned cvtpk_bf16(float lo, float hi){
  unsigned r; asm("v_cvt_pk_bf16_f32 %0, %1, %2" : "=v"(r) : "v"(lo), "v"(hi)); return r;
}

static __device__ __forceinline__ void gload_lds16(const void* g, void* l){
  __builtin_amdgcn_global_load_lds((__attribute__((address_space(1))) void*)g,
                                   (__attribute__((address_space(3))) void*)l,
                                   16, 0, 0);
}

// ---------- f32 -> bf16 conversion ----------
__global__ void cvt_bf16(const float* __restrict__ src, unsigned short* __restrict__ dst,
                         int n4, float scale){
  int i = blockIdx.x * blockDim.x + threadIdx.x;
  if (i >= n4) return;
  float4 v = reinterpret_cast<const float4*>(src)[i];
  ushort4 o;
  o.x = f2bf(v.x * scale); o.y = f2bf(v.y * scale);
  o.z = f2bf(v.z * scale); o.w = f2bf(v.w * scale);
  reinterpret_cast<ushort4*>(dst)[i] = o;
}

// ---------- mask expansion with layout auto-detection ----------
__global__ void expand_mask(const unsigned* __restrict__ raw, int* __restrict__ out, int n){
  __shared__ int sInt, sFlt;
  int t = threadIdx.x;
  if (t == 0){ sInt = 1; sFlt = 1; }
  __syncthreads();
  int okI = 1, okF = 1;
  for (int i = t; i < n/4; i += blockDim.x){
    unsigned u = raw[i];
    okI &= (u <= 1u);
    okF &= (u == 0u || u == 0x3f800000u);
  }
  if (!okI) atomicAnd(&sInt, 0);
  if (!okF) atomicAnd(&sFlt, 0);
  __syncthreads();
  if (sInt || sFlt){
    for (int i = t; i < n; i += blockDim.x) out[i] = (raw[i] != 0u);
  } else {
    const unsigned char* rb = (const unsigned char*)raw;
    for (int i = t; i < n; i += blockDim.x) out[i] = (rb[i] != 0);
  }
}

// ---------- bf16 NT GEMM (verified round 0) ----------
template<typename CT>
__global__ __launch_bounds__(256) void gemm_bt(const unsigned short* __restrict__ A,
                                               const unsigned short* __restrict__ Bm,
                                               CT* __restrict__ C,
                                               int M, int N, int K){
  __shared__ unsigned short As[128*32];
  __shared__ unsigned short Bs[128*32];
  const int t = threadIdx.x;
  const int w = t >> 6, l = t & 63;
  const int wr = w >> 1, wc = w & 1;
  const int br = blockIdx.y * 128, bc = blockIdx.x * 128;

  f32x4 acc[4][4];
  const f32x4 fz = {0.f,0.f,0.f,0.f};
  #pragma unroll
  for (int m=0;m<4;m++)
    #pragma unroll
    for (int n=0;n<4;n++) acc[m][n] = fz;

  const int lrow = l >> 2;
  const int lk   = (l & 3) * 8;
  const int fr   = l & 15;
  const int fk   = (l >> 4) * 8;

  for (int k0 = 0; k0 < K; k0 += 32){
    #pragma unroll
    for (int it = 0; it < 2; ++it){
      const int rb = it*64 + w*16;
      gload_lds16(A  + (size_t)(br + rb + lrow)*K + k0 + lk, &As[rb*32]);
      gload_lds16(Bm + (size_t)(bc + rb + lrow)*K + k0 + lk, &Bs[rb*32]);
    }
    __syncthreads();
    bf16x8 a[4], b[4];
    #pragma unroll
    for (int m=0;m<4;m++)
      a[m] = *reinterpret_cast<const bf16x8*>(&As[(wr*64 + m*16 + fr)*32 + fk]);
    #pragma unroll
    for (int n=0;n<4;n++)
      b[n] = *reinterpret_cast<const bf16x8*>(&Bs[(wc*64 + n*16 + fr)*32 + fk]);
    #pragma unroll
    for (int m=0;m<4;m++)
      #pragma unroll
      for (int n=0;n<4;n++)
        acc[m][n] = MFMA16(a[m], b[n], acc[m][n]);
    __syncthreads();
  }

  const int orow0 = br + wr*64 + (l >> 4)*4;
  const int ocol0 = bc + wc*64 + (l & 15);
  #pragma unroll
  for (int m=0;m<4;m++)
    #pragma unroll
    for (int n=0;n<4;n++)
      #pragma unroll
      for (int r=0;r<4;r++){
        const size_t idx = (size_t)(orow0 + m*16 + r) * N + (ocol0 + n*16);
        float v = acc[m][n][r];
        if constexpr (sizeof(CT) == 2) C[idx] = (CT)f2bf(v);
        else                           C[idx] = v;
      }
}

// ---------- V transpose: QKV V-region -> VtG[(b*H+h)*64 + d][T] ----------
__global__ __launch_bounds__(256) void vtrans(const unsigned short* __restrict__ QKV,
                                              unsigned short* __restrict__ VtG){
  __shared__ unsigned short st[64][72];   // padded rows
  const int t = threadIdx.x;
  const int token0 = blockIdx.x * 64;
  const int bh = blockIdx.y;
  const int b = bh / Hc, h = bh - b * Hc;
  const size_t tokbase = (size_t)b * Tc;

  const int tok = t >> 2;
  const unsigned short* src = QKV + (tokbase + token0 + tok) * (size_t)QKV_LD + 1536 + h*64;
  #pragma unroll
  for (int i = 0; i < 2; ++i){
    const int ul = (t & 3)*2 + i;
    *reinterpret_cast<uint4*>(&st[tok][ul*8]) =
        *reinterpret_cast<const uint4*>(src + ul*8);
  }
  __syncthreads();
  const int d = t >> 2;
  #pragma unroll
  for (int half = 0; half < 2; ++half){
    union { unsigned short s[8]; uint4 q; } tmp;
    const int tk0 = (t & 3)*8 + half*32;
    #pragma unroll
    for (int j = 0; j < 8; ++j)
      tmp.s[j] = st[tk0 + j][d];
    *reinterpret_cast<uint4*>(VtG + ((size_t)(bh*64 + d))*Tc + token0 + tk0) = tmp.q;
  }
}

// ---------- flash attention: 2-buffer, counted-wait raw barriers, 4 blocks/CU ----------
// grid (T/128, B*H); 4 waves x 32 q-rows; KV chunk = 64.
// Per iter c: QK(c) -> issue stage(c+1) -> softmax(c) -> PV(c) -> Ms(c+1)
//             -> s_waitcnt vmcnt(0) lgkmcnt(0) + raw s_barrier.
// LDS 33.3KB -> 4 blocks/CU (round-6's 3rd buffer bought nothing; TLP was the limit).
__global__ __launch_bounds__(256, 4) void attn(const unsigned short* __restrict__ QKV,
                                               const unsigned short* __restrict__ VtG,
                                               const int* __restrict__ mask,
                                               unsigned short* __restrict__ AO){
  __shared__ unsigned short Ks[2][64*64];  // K chunk, source-swizzled (16B units: c ^= row&7)
  __shared__ unsigned short Vs[2][64*64];  // V^T chunk [d][key], same source swizzle
  __shared__ float Ms[2][64];              // additive key-mask bias

  const int t = threadIdx.x, w = t >> 6, l = t & 63;
  const int bh = blockIdx.y;
  const int b  = bh / Hc, h = bh - b * Hc;
  const int q0 = blockIdx.x * 128 + w * 32;
  const int fr = l & 15, fg = l >> 4;

  const size_t tokbase = (size_t)b * Tc;
  const unsigned short* Qp = QKV + (tokbase + q0) * (size_t)QKV_LD + h*64;
  const unsigned short* Kbase = QKV + tokbase * (size_t)QKV_LD + h*64 + 768;
  const unsigned short* VtB = VtG + (size_t)(bh*64) * Tc;
  const int* bm = mask + b * Tc;

  // Q fragments: Q[q=mc*16+fr][k=ks*32+fg*8+j]
  bf16x8 qa[2][2];
  #pragma unroll
  for (int mc=0; mc<2; mc++)
    #pragma unroll
    for (int ks=0; ks<2; ks++)
      qa[mc][ks] = *reinterpret_cast<const bf16x8*>(
          Qp + (size_t)(mc*16+fr)*QKV_LD + ks*32 + fg*8);

  // wave 0: preload all 32 chunk-mask bits for its lane's key slot
  unsigned bits = 0;
  if (w == 0){
    #pragma unroll
    for (int cc = 0; cc < 32; ++cc)
      bits |= (unsigned)(bm[cc*64 + l] != 0) << cc;
  }

  const f32x4 fz = {0.f,0.f,0.f,0.f};
  f32x4 accT[2][4];
  #pragma unroll
  for (int mc=0; mc<2; mc++)
    #pragma unroll
    for (int n=0; n<4; n++) accT[mc][n] = fz;
  float mrow[2] = {-1e30f, -1e30f};
  float lsum[2] = {0.f, 0.f};

  // ---- staging helper (4 gload_lds16 per thread per chunk, all waves) ----
  const int srow = l >> 3, scol = (l & 7) ^ (l >> 3);   // source swizzle
  auto stage = [&](int c){
    const int key0 = c * 64, buf = c & 1;
    #pragma unroll
    for (int i=0; i<2; i++){
      const int rb = w*16 + i*8;      // K rows
      gload_lds16(Kbase + (size_t)(key0 + rb + srow)*QKV_LD + scol*8,
                  &Ks[buf][rb*64]);
    }
    #pragma unroll
    for (int i=0; i<2; i++){
      const int rb = (w*2 + i)*8;     // V^T rows (d)
      gload_lds16(VtB + (size_t)(rb + srow)*Tc + key0 + scol*8,
                  &Vs[buf][rb*64]);
    }
  };

  // ---- prologue: stage chunk 0
  stage(0);
  if (w == 0) Ms[0][l] = (bits & 1u) ? -1e9f : 0.f;
  asm volatile("s_waitcnt vmcnt(0) lgkmcnt(0)" ::: "memory");
  __builtin_amdgcn_s_barrier();
  asm volatile("" ::: "memory");

  #pragma unroll 2
  for (int c = 0; c < 32; ++c){
    const int cb = c & 1;

    // ---- QK^T swapped: S^T[key][q], mask bias as C-init
    f32x4 S[2][4];
    __builtin_amdgcn_s_setprio(1);
    #pragma unroll
    for (int g=0; g<4; g++){
      f32x4 mb = *reinterpret_cast<const f32x4*>(&Ms[cb][g*16 + fg*4]);
      S[0][g] = mb; S[1][g] = mb;
      #pragma unroll
      for (int ks=0; ks<2; ks++){
        const int row = g*16 + fr;
        bf16x8 kf = *reinterpret_cast<const bf16x8*>(
            &Ks[cb][row*64 + (((ks*4+fg) ^ (row&7))*8)]);
        S[0][g] = MFMA16(kf, qa[0][ks], S[0][g]);
        S[1][g] = MFMA16(kf, qa[1][ks], S[1][g]);
      }
    }
    __builtin_amdgcn_s_setprio(0);

    // ---- issue stage(c+1): flies under softmax + PV (T14)
    if (c + 1 < 32) stage(c + 1);

    // ---- softmax(c): in-lane 16 keys (max3 tree) + 2 shfls; P packed in regs
    unsigned pkAll[2][4][2];
    #pragma unroll
    for (int mc=0; mc<2; mc++){
      float a0 = max3f(S[mc][0][0], S[mc][0][1], S[mc][0][2]);
      float a1 = max3f(S[mc][0][3], S[mc][1][0], S[mc][1][1]);
      float a2 = max3f(S[mc][1][2], S[mc][1][3], S[mc][2][0]);
      float a3 = max3f(S[mc][2][1], S[mc][2][2], S[mc][2][3]);
      float a4 = max3f(S[mc][3][0], S[mc][3][1], S[mc][3][2]);
      float cm = fmaxf(max3f(a0, a1, a2), max3f(a3, a4, S[mc][3][3]));
      cm = fmaxf(cm, __shfl_xor(cm, 16));
      cm = fmaxf(cm, __shfl_xor(cm, 32));
      if (!__all(cm <= mrow[mc] + 8.0f)){     // defer-max (T13)
        const float nm = fmaxf(mrow[mc], cm);
        const float sc = exp2a(mrow[mc] - nm);
        lsum[mc] *= sc;
        #pragma unroll
        for (int n=0; n<4; n++) accT[mc][n] = accT[mc][n] * sc;
        mrow[mc] = nm;
      }
      float ps = 0.f;
      #pragma unroll
      for (int g=0; g<4; g++){
        const float p0 = exp2a(S[mc][g][0] - mrow[mc]);
        const float p1 = exp2a(S[mc][g][1] - mrow[mc]);
        const float p2 = exp2a(S[mc][g][2] - mrow[mc]);
        const float p3 = exp2a(S[mc][g][3] - mrow[mc]);
        ps += (p0 + p1) + (p2 + p3);
        pkAll[mc][g][0] = cvtpk_bf16(p0, p1);
        pkAll[mc][g][1] = cvtpk_bf16(p2, p3);
      }
      ps += __shfl_xor(ps, 16);
      ps += __shfl_xor(ps, 32);
      lsum[mc] += ps;
    }

    // ---- PV swapped: O^T += V^T * P^T (permuted k-order, lane-local P)
    __builtin_amdgcn_s_setprio(1);
    #pragma unroll
    for (int ks2=0; ks2<2; ks2++){
      union PBu { unsigned u[4]; bf16x8 v; } pb0, pb1;
      pb0.u[0] = pkAll[0][ks2*2][0];   pb0.u[1] = pkAll[0][ks2*2][1];
      pb0.u[2] = pkAll[0][ks2*2+1][0]; pb0.u[3] = pkAll[0][ks2*2+1][1];
      pb1.u[0] = pkAll[1][ks2*2][0];   pb1.u[1] = pkAll[1][ks2*2][1];
      pb1.u[2] = pkAll[1][ks2*2+1][0]; pb1.u[3] = pkAll[1][ks2*2+1][1];
      #pragma unroll
      for (int n=0; n<4; n++){
        const int row = n*16 + fr;
        union VA { u16x4 h[2]; bf16x8 v; } va;
        va.h[0] = *reinterpret_cast<const u16x4*>(
            &Vs[cb][row*64 + (((ks2*4     + (fg>>1)) ^ (row&7))*8) + (fg&1)*4]);
        va.h[1] = *reinterpret_cast<const u16x4*>(
            &Vs[cb][row*64 + (((ks2*4 + 2 + (fg>>1)) ^ (row&7))*8) + (fg&1)*4]);
        accT[0][n] = MFMA16(va.v, pb0.v, accT[0][n]);
        accT[1][n] = MFMA16(va.v, pb1.v, accT[1][n]);
      }
    }
    __builtin_amdgcn_s_setprio(0);

    // ---- Ms(c+1) from register bits (no VMEM)
    if (w == 0 && c + 1 < 32)
      Ms[cb^1][l] = ((bits >> (c+1)) & 1u) ? -1e9f : 0.f;

    // ---- wait stage(c+1) landed + all LDS ops done, then barrier
    if (c < 31){
      asm volatile("s_waitcnt vmcnt(0) lgkmcnt(0)" ::: "memory");
      __builtin_amdgcn_s_barrier();
      asm volatile("" ::: "memory");
    }
  }

  // ---- epilogue: normalize, zero q-padded rows, packed 8B stores
  #pragma unroll
  for (int mc=0; mc<2; mc++){
    const int qrow = q0 + mc*16 + fr;
    const int qm = bm[qrow];
    const float inv = (qm || lsum[mc] <= 0.f) ? 0.f : 1.f / lsum[mc];
    #pragma unroll
    for (int n=0; n<4; n++){
      ushort4 o;
      o.x = f2bf(accT[mc][n][0] * inv);
      o.y = f2bf(accT[mc][n][1] * inv);
      o.z = f2bf(accT[mc][n][2] * inv);
      o.w = f2bf(accT[mc][n][3] * inv);
      *reinterpret_cast<ushort4*>(
          &AO[(tokbase + qrow) * (size_t)Dc + h*64 + n*16 + fg*4]) = o;
    }
  }
}

// ---------- launch ----------
extern "C" void kernel_launch(void* const* d_in, const int* in_sizes, int n_in,
                              void* d_out, int out_size, void* d_ws, size_t ws_size,
                              hipStream_t stream){
  const float* h    = (const float*)d_in[0];
  const unsigned* m = (const unsigned*)d_in[1];
  const float* Wq   = (const float*)d_in[2];
  const float* Wk   = (const float*)d_in[3];
  const float* Wv   = (const float*)d_in[4];
  const float* Wo   = (const float*)d_in[5];
  float* out        = (float*)d_out;

  unsigned short* hb   = (unsigned short*)d_ws;       // 8192*768 (reused as VtG after gemm1)
  unsigned short* Wqkv = hb   + (size_t)NTOK * Dc;    // 2304*768
  unsigned short* Wob  = Wqkv + (size_t)QKV_LD * Dc;  // 768*768
  unsigned short* QKV  = Wob  + (size_t)Dc * Dc;      // 8192*2304
  unsigned short* AO   = QKV  + (size_t)NTOK * QKV_LD;// 8192*768
  int* mexp            = (int*)(AO + (size_t)NTOK * Dc);

  const size_t need = ((size_t)NTOK*Dc + (size_t)QKV_LD*Dc + (size_t)Dc*Dc +
                       (size_t)NTOK*QKV_LD + (size_t)NTOK*Dc) * 2 + (size_t)NTOK*4;
  if (ws_size < need) return;

  const int W2 = Dc * Dc;
  // Wq folded with (1/8)*log2e -> scores in log2 domain for exp2 softmax
  cvt_bf16<<<(NTOK*Dc/4 + 255)/256, 256, 0, stream>>>(h,  hb,          NTOK*Dc/4, 1.0f);
  cvt_bf16<<<(W2/4 + 255)/256,      256, 0, stream>>>(Wq, Wqkv,        W2/4, 0.125f*1.44269504f);
  cvt_bf16<<<(W2/4 + 255)/256,      256, 0, stream>>>(Wk, Wqkv + W2,   W2/4, 1.0f);
  cvt_bf16<<<(W2/4 + 255)/256,      256, 0, stream>>>(Wv, Wqkv + 2*W2, W2/4, 1.0f);
  cvt_bf16<<<(W2/4 + 255)/256,      256, 0, stream>>>(Wo, Wob,         W2/4, 1.0f);
  expand_mask<<<1, 256, 0, stream>>>(m, mexp, NTOK);

  gemm_bt<unsigned short><<<dim3(QKV_LD/128, NTOK/128), 256, 0, stream>>>(
      hb, Wqkv, QKV, NTOK, QKV_LD, Dc);

  // V^T into the now-dead hb buffer
  unsigned short* VtG = hb;
  vtrans<<<dim3(Tc/64, Bc*Hc), 256, 0, stream>>>(QKV, VtG);

  attn<<<dim3(Tc/128, Bc*Hc), 256, 0, stream>>>(QKV, VtG, mexp, AO);

  gemm_bt<float><<<dim3(Dc/128, NTOK/128), 256, 0, stream>>>(
      AO, Wob, out, NTOK, Dc, Dc);
}